// Round 7
// baseline (1009.373 us; speedup 1.0000x reference)
//
#include <hip/hip_runtime.h>

// Problem constants (match reference)
#define NX_ 432
#define NY_ 496
#define C_  64
#define B_  4
#define CELLS_ (NX_ * NY_)            // 214272 cells per (bin, batch) canvas plane
#define PLANE_ ((size_t)CELLS_)       // c-plane stride in floats
#define BATCH_STRIDE_ ((size_t)C_ * CELLS_)        // 13,713,408 floats
#define BIN_STRIDE_   ((size_t)B_ * C_ * CELLS_)   // 54,853,632 floats
#define MAP_BIN_ ((size_t)B_ * CELLS_)             // map entries per bin

typedef float vfloat4 __attribute__((ext_vector_type(4)));
typedef int   vint4   __attribute__((ext_vector_type(4)));

// ---------------------------------------------------------------------------
// Kernel 1: scatter pillar index p into map[bin][b*CELLS + z + y*NX + x]
// ---------------------------------------------------------------------------
__global__ __launch_bounds__(256) void scatter_idx_kernel(
    const int* __restrict__ coords0,
    const int* __restrict__ coords1,
    const int* __restrict__ coords2,
    int* __restrict__ map, int npil)
{
    const int bin = blockIdx.y;
    const int p = blockIdx.x * 256 + threadIdx.x;
    if (p >= npil) return;
    const int* coords = (bin == 0) ? coords0 : (bin == 1) ? coords1 : coords2;
    vint4 c = ((const vint4*)coords)[p];
    size_t idx = (size_t)bin * MAP_BIN_ + (size_t)c.x * CELLS_ + c.y + c.z * NX_ + c.w;
    map[idx] = p;
}

// ---------------------------------------------------------------------------
// Kernel 2 — ROUND 7 DIAGNOSTIC BUILD v2 (correctness-preserving).
//
// Round-6 (store-only replay, pstride=0) measured the L2-HIT store rate
// (41.5 us / 658 MB pass) because same-address re-stores never leave L2 —
// store issue is NOT the limiter, but the gather (~333 us) still did not
// surface above the ~425 us poison fills, so FETCH_SIZE/WRITE_SIZE remain
// unread.
//
// v2: replay the FULL body (map load + pf loads + selects + stores) npass=5
// times. Load and store base pointers are offset by runtime-opaque ZERO
// strides (mstride/pstride/ostride) so the compiler can neither hoist the
// loads out of the pass loop nor merge the stores; every pass touches the
// same addresses with the same values -> output exact, absmax 0.
//
// Purpose: gather dur ~= 250 + 4*D_full > 430 us -> surfaces in top-5 with
// its own FETCH_SIZE / WRITE_SIZE / VALUBusy / Occupancy for the first
// time. D_full (vs 41 us store-only) splits hot-load cost from store cost.
// Decision rules (round 8): FETCH >> 300 MB -> read amplification;
// WRITE >> ~1 GB -> write/sector amplification; both ~ideal & D_full small
// -> pass-0 is cold/structural -> near-roofline, recover residuals only.
// ---------------------------------------------------------------------------
__global__ __launch_bounds__(256) void gather_split_kernel(
    const float* __restrict__ pf0,
    const float* __restrict__ pf1,
    const float* __restrict__ pf2,
    const int* __restrict__ map,
    float* __restrict__ out,
    int npass, size_t mstride, size_t fstride, size_t ostride)
{
    const int g   = blockIdx.y;           // plane-group: channels 4g..4g+3
    const int zb  = blockIdx.z;           // bin*B_ + b
    const int bin = zb >> 2;
    const int b   = zb & 3;

    const int cell = blockIdx.x * 1024 + threadIdx.x * 4;
    if (cell >= CELLS_) return;

    const float* __restrict__ pf = (bin == 0) ? pf0 : (bin == 1) ? pf1 : pf2;

    const int* mbase = map + (size_t)bin * MAP_BIN_ + (size_t)b * CELLS_ + cell;
    float* obase = out + (size_t)bin * BIN_STRIDE_ + (size_t)b * BATCH_STRIDE_ + cell;

    for (int pass = 0; pass < npass; ++pass) {
        // Runtime-opaque offsets (== 0): compiler cannot hoist/merge across
        // passes; hardware sees identical addresses every pass.
        const int* m = mbase + (size_t)pass * mstride;
        const float* pfp = pf + (size_t)pass * fstride;
        float* o = obase + (size_t)pass * ostride;

        vint4 idx = *(const vint4*)m;

        const bool v0 = idx.x >= 0, v1 = idx.y >= 0, v2 = idx.z >= 0, v3 = idx.w >= 0;
        // Clamp invalid to row 0: always-safe address, unconditional 16B loads.
        const vfloat4 x0 = *(const vfloat4*)(pfp + (size_t)(v0 ? idx.x : 0) * C_ + 4 * g);
        const vfloat4 x1 = *(const vfloat4*)(pfp + (size_t)(v1 ? idx.y : 0) * C_ + 4 * g);
        const vfloat4 x2 = *(const vfloat4*)(pfp + (size_t)(v2 ? idx.z : 0) * C_ + 4 * g);
        const vfloat4 x3 = *(const vfloat4*)(pfp + (size_t)(v3 ? idx.w : 0) * C_ + 4 * g);

#pragma unroll
        for (int q = 0; q < 4; ++q) {
            vfloat4 w;
            w.x = v0 ? x0[q] : 0.0f;
            w.y = v1 ? x1[q] : 0.0f;
            w.z = v2 ? x2[q] : 0.0f;
            w.w = v3 ? x3[q] : 0.0f;
            *(vfloat4*)(o + (size_t)(4 * g + q) * PLANE_) = w;
        }
    }
}

extern "C" void kernel_launch(void* const* d_in, const int* in_sizes, int n_in,
                              void* d_out, int out_size, void* d_ws, size_t ws_size,
                              hipStream_t stream) {
    const float* pf0 = (const float*)d_in[0];
    const int*   co0 = (const int*)d_in[1];
    const float* pf1 = (const float*)d_in[2];
    const int*   co1 = (const int*)d_in[3];
    const float* pf2 = (const float*)d_in[4];
    const int*   co2 = (const int*)d_in[5];
    float* out = (float*)d_out;

    const int npil = in_sizes[1] / 4;   // rows in coords (B*P_PER)

    int* map = (int*)d_ws;
    const size_t map_bytes = 3 * MAP_BIN_ * sizeof(int);

    // init map to -1 (0xFFFFFFFF) — ~10 MB, ~2 us
    (void)hipMemsetAsync(map, 0xFF, map_bytes, stream);

    dim3 g1((npil + 255) / 256, 3, 1);
    scatter_idx_kernel<<<g1, 256, 0, stream>>>(co0, co1, co2, map, npil);

    // DIAGNOSTIC: npass=5 full-body replays, all opaque strides = 0.
    dim3 g2((CELLS_ + 1023) / 1024, C_ / 4, 3 * B_);
    gather_split_kernel<<<g2, 256, 0, stream>>>(pf0, pf1, pf2, map, out,
                                                5, (size_t)0, (size_t)0, (size_t)0);
}

// Round 8
// 698.789 us; speedup vs baseline: 1.4445x; 1.4445x over previous
//
#include <hip/hip_runtime.h>

// Problem constants (match reference)
#define NX_ 432
#define NY_ 496
#define C_  64
#define B_  4
#define CELLS_ (NX_ * NY_)            // 214272 cells per (bin, batch) canvas plane
#define PLANE_ ((size_t)CELLS_)       // c-plane stride in floats
#define BATCH_STRIDE_ ((size_t)C_ * CELLS_)        // 13,713,408 floats
#define BIN_STRIDE_   ((size_t)B_ * C_ * CELLS_)   // 54,853,632 floats
#define MAP_BIN_ ((size_t)B_ * CELLS_)             // map entries per bin

typedef float vfloat4 __attribute__((ext_vector_type(4)));
typedef int   vint4   __attribute__((ext_vector_type(4)));

// ---------------------------------------------------------------------------
// Kernel 1: scatter pillar index p into map[bin][b*CELLS + z + y*NX + x]
// ---------------------------------------------------------------------------
__global__ __launch_bounds__(256) void scatter_idx_kernel(
    const int* __restrict__ coords0,
    const int* __restrict__ coords1,
    const int* __restrict__ coords2,
    int* __restrict__ map, int npil)
{
    const int bin = blockIdx.y;
    const int p = blockIdx.x * 256 + threadIdx.x;
    if (p >= npil) return;
    const int* coords = (bin == 0) ? coords0 : (bin == 1) ? coords1 : coords2;
    vint4 c = ((const vint4*)coords)[p];
    size_t idx = (size_t)bin * MAP_BIN_ + (size_t)c.x * CELLS_ + c.y + c.z * NX_ + c.w;
    map[idx] = p;
}

// ---------------------------------------------------------------------------
// Kernel 2 (round 8): READ-BATCHED plane-split gather.
//
// r7 diagnostic established: gather ~153 us at ~5 TB/s vs 114 us floor;
// FETCH = ideal 60 MB (no read amplification), WRITE drains ~1x (no write
// amplification); replay passes hit 6.3+ TB/s. The residual gap is mixed-
// stream inefficiency: r5 alternated 5 scattered read requests with 4 store
// bursts per thread. This version batches 4x more reads ahead of a 4x
// longer store burst:
//   each block owns 16 planes (channels 16*g4 .. 16*g4+15);
//   per thread: 1 map vint4 + 16 pf float4 loads (each of the thread's 4
//   pillar rows contributes ONE aligned 64 B segment = ideal sectors),
//   then 16 dense stores (1 KB contiguous per wave-instruction, the exact
//   r5 store shape).
// Device-wide: read requests /4, map logical re-reads /4 (160->40 MB),
// read/write bus turnarounds /4. ~100 VGPR, no LDS, no barriers.
// ---------------------------------------------------------------------------
__global__ __launch_bounds__(256) void gather_batch_kernel(
    const float* __restrict__ pf0,
    const float* __restrict__ pf1,
    const float* __restrict__ pf2,
    const int* __restrict__ map,
    float* __restrict__ out)
{
    const int g4  = blockIdx.y;           // plane-supergroup: channels 16g4..16g4+15
    const int zb  = blockIdx.z;           // bin*B_ + b
    const int bin = zb >> 2;
    const int b   = zb & 3;

    const int cell = blockIdx.x * 1024 + threadIdx.x * 4;
    if (cell >= CELLS_) return;           // no barriers -> early-out safe

    const float* __restrict__ pf = (bin == 0) ? pf0 : (bin == 1) ? pf1 : pf2;

    const int* m = map + (size_t)bin * MAP_BIN_ + (size_t)b * CELLS_ + cell;
    vint4 idx = *(const vint4*)m;

    const bool v0 = idx.x >= 0, v1 = idx.y >= 0, v2 = idx.z >= 0, v3 = idx.w >= 0;
    // Clamp invalid to row 0: always-safe address, unconditional loads.
    // Each row's 16 channels [16g4, 16g4+16) = one aligned 64 B segment.
    const float* r0 = pf + (size_t)(v0 ? idx.x : 0) * C_ + 16 * g4;
    const float* r1 = pf + (size_t)(v1 ? idx.y : 0) * C_ + 16 * g4;
    const float* r2 = pf + (size_t)(v2 ? idx.z : 0) * C_ + 16 * g4;
    const float* r3 = pf + (size_t)(v3 ? idx.w : 0) * C_ + 16 * g4;

    // Batch ALL 16 reads (4 rows x 4 float4) before any store: the compiler
    // issues 16 global_load_dwordx4 back-to-back, then the store burst
    // drains them in load order via decreasing vmcnt waits.
    vfloat4 x0[4], x1[4], x2[4], x3[4];
#pragma unroll
    for (int k = 0; k < 4; ++k) {
        x0[k] = *(const vfloat4*)(r0 + 4 * k);
        x1[k] = *(const vfloat4*)(r1 + 4 * k);
        x2[k] = *(const vfloat4*)(r2 + 4 * k);
        x3[k] = *(const vfloat4*)(r3 + 4 * k);
    }

    float* o = out + (size_t)bin * BIN_STRIDE_ + (size_t)b * BATCH_STRIDE_
                   + (size_t)(16 * g4) * PLANE_ + cell;

    // 16 dense stores: plane 16g4+4k+q, 1 KB contiguous per wave-inst.
#pragma unroll
    for (int k = 0; k < 4; ++k) {
#pragma unroll
        for (int q = 0; q < 4; ++q) {
            vfloat4 w;
            w.x = v0 ? x0[k][q] : 0.0f;
            w.y = v1 ? x1[k][q] : 0.0f;
            w.z = v2 ? x2[k][q] : 0.0f;
            w.w = v3 ? x3[k][q] : 0.0f;
            *(vfloat4*)(o + (size_t)(4 * k + q) * PLANE_) = w;
        }
    }
}

extern "C" void kernel_launch(void* const* d_in, const int* in_sizes, int n_in,
                              void* d_out, int out_size, void* d_ws, size_t ws_size,
                              hipStream_t stream) {
    const float* pf0 = (const float*)d_in[0];
    const int*   co0 = (const int*)d_in[1];
    const float* pf1 = (const float*)d_in[2];
    const int*   co1 = (const int*)d_in[3];
    const float* pf2 = (const float*)d_in[4];
    const int*   co2 = (const int*)d_in[5];
    float* out = (float*)d_out;

    const int npil = in_sizes[1] / 4;   // rows in coords (B*P_PER)

    int* map = (int*)d_ws;
    const size_t map_bytes = 3 * MAP_BIN_ * sizeof(int);

    // init map to -1 (0xFFFFFFFF) — ~10 MB, ~2 us
    (void)hipMemsetAsync(map, 0xFF, map_bytes, stream);

    dim3 g1((npil + 255) / 256, 3, 1);
    scatter_idx_kernel<<<g1, 256, 0, stream>>>(co0, co1, co2, map, npil);

    // x: 210 cell-chunks (fastest -> dense write frontier), y: 4 plane-
    // supergroups (16 planes each), z: 12 (bin,b) pairs. 10080 blocks.
    dim3 g2((CELLS_ + 1023) / 1024, C_ / 16, 3 * B_);
    gather_batch_kernel<<<g2, 256, 0, stream>>>(pf0, pf1, pf2, map, out);
}

// Round 9
// 685.124 us; speedup vs baseline: 1.4733x; 1.0199x over previous
//
#include <hip/hip_runtime.h>

// Problem constants (match reference)
#define NX_ 432
#define NY_ 496
#define C_  64
#define B_  4
#define CELLS_ (NX_ * NY_)            // 214272 cells per (bin, batch) canvas plane
#define PLANE_ ((size_t)CELLS_)       // c-plane stride in floats
#define BATCH_STRIDE_ ((size_t)C_ * CELLS_)        // 13,713,408 floats
#define BIN_STRIDE_   ((size_t)B_ * C_ * CELLS_)   // 54,853,632 floats
#define MAP_BIN_ ((size_t)B_ * CELLS_)             // map entries per bin

typedef float vfloat4 __attribute__((ext_vector_type(4)));
typedef int   vint4   __attribute__((ext_vector_type(4)));

// ---------------------------------------------------------------------------
// Kernel 1: scatter pillar index p into map[bin][b*CELLS + z + y*NX + x]
// coords layout per row: [b, z, y, x] int32. Cells are unique per sample.
// ---------------------------------------------------------------------------
__global__ __launch_bounds__(256) void scatter_idx_kernel(
    const int* __restrict__ coords0,
    const int* __restrict__ coords1,
    const int* __restrict__ coords2,
    int* __restrict__ map, int npil)
{
    const int bin = blockIdx.y;
    const int p = blockIdx.x * 256 + threadIdx.x;
    if (p >= npil) return;
    const int* coords = (bin == 0) ? coords0 : (bin == 1) ? coords1 : coords2;
    vint4 c = ((const vint4*)coords)[p];
    size_t idx = (size_t)bin * MAP_BIN_ + (size_t)c.x * CELLS_ + c.y + c.z * NX_ + c.w;
    map[idx] = p;
}

// ---------------------------------------------------------------------------
// Kernel 2: PLANE-GROUP-SPLIT gather — the verified session best (684.4 us,
// round 5). Each block writes 4 planes; blockIdx.x fastest-varying keeps the
// ~2048 co-resident blocks on a DENSE ~40 MB advancing write frontier
// (fill-like) instead of scattering 4 KB chunks across the 658 MB output.
//
// Counter-verified properties (r7 diagnostic): FETCH = ideal 60 MB/pass (all
// map/pf re-reads L2/L3-absorbed), WRITE drains ~1x (no sector
// amplification), occupancy 86%, VALU 12%. Gather ~153 us vs 114 us traffic
// floor; the residual is the compulsory cold scattered 64 B pf reads mixed
// with the dense write drain (hot-replay of the same instruction stream
// sustains >6.3 TB/s -> instruction mix is not the limit).
//
// Per thread: 1x16B map load, 4x16B pf loads (channels 4g..4g+3 = bytes
// [16g,16g+16) of a pillar row = one aligned float4), 4x16B stores.
// No LDS, no barriers. Branchless: invalid idx (<0) clamps to row 0
// (always-safe address), loaded unconditionally, zero selected in after.
// ---------------------------------------------------------------------------
__global__ __launch_bounds__(256) void gather_split_kernel(
    const float* __restrict__ pf0,
    const float* __restrict__ pf1,
    const float* __restrict__ pf2,
    const int* __restrict__ map,
    float* __restrict__ out)
{
    const int g   = blockIdx.y;           // plane-group: channels 4g..4g+3
    const int zb  = blockIdx.z;           // bin*B_ + b
    const int bin = zb >> 2;
    const int b   = zb & 3;

    const int cell = blockIdx.x * 1024 + threadIdx.x * 4;
    if (cell >= CELLS_) return;

    const float* __restrict__ pf = (bin == 0) ? pf0 : (bin == 1) ? pf1 : pf2;

    const int* m = map + (size_t)bin * MAP_BIN_ + (size_t)b * CELLS_ + cell;
    vint4 idx = *(const vint4*)m;

    const bool v0 = idx.x >= 0, v1 = idx.y >= 0, v2 = idx.z >= 0, v3 = idx.w >= 0;
    // Clamp invalid to row 0: always-safe address, unconditional 16B loads.
    const vfloat4 x0 = *(const vfloat4*)(pf + (size_t)(v0 ? idx.x : 0) * C_ + 4 * g);
    const vfloat4 x1 = *(const vfloat4*)(pf + (size_t)(v1 ? idx.y : 0) * C_ + 4 * g);
    const vfloat4 x2 = *(const vfloat4*)(pf + (size_t)(v2 ? idx.z : 0) * C_ + 4 * g);
    const vfloat4 x3 = *(const vfloat4*)(pf + (size_t)(v3 ? idx.w : 0) * C_ + 4 * g);

    float* o = out + (size_t)bin * BIN_STRIDE_ + (size_t)b * BATCH_STRIDE_ + cell;

#pragma unroll
    for (int q = 0; q < 4; ++q) {
        vfloat4 w;
        w.x = v0 ? x0[q] : 0.0f;
        w.y = v1 ? x1[q] : 0.0f;
        w.z = v2 ? x2[q] : 0.0f;
        w.w = v3 ? x3[q] : 0.0f;
        *(vfloat4*)(o + (size_t)(4 * g + q) * PLANE_) = w;
    }
}

extern "C" void kernel_launch(void* const* d_in, const int* in_sizes, int n_in,
                              void* d_out, int out_size, void* d_ws, size_t ws_size,
                              hipStream_t stream) {
    const float* pf0 = (const float*)d_in[0];
    const int*   co0 = (const int*)d_in[1];
    const float* pf1 = (const float*)d_in[2];
    const int*   co1 = (const int*)d_in[3];
    const float* pf2 = (const float*)d_in[4];
    const int*   co2 = (const int*)d_in[5];
    float* out = (float*)d_out;

    const int npil = in_sizes[1] / 4;   // rows in coords (B*P_PER)

    int* map = (int*)d_ws;
    const size_t map_bytes = 3 * MAP_BIN_ * sizeof(int);

    // init map to -1 (0xFFFFFFFF) — ~10 MB, ~2 us
    (void)hipMemsetAsync(map, 0xFF, map_bytes, stream);

    dim3 g1((npil + 255) / 256, 3, 1);
    scatter_idx_kernel<<<g1, 256, 0, stream>>>(co0, co1, co2, map, npil);

    // x: 210 cell-chunks (fastest -> dense write frontier), y: 16 plane-
    // groups, z: 12 (bin,b) pairs. 40320 blocks, 4 loads + 4 stores/thread.
    dim3 g2((CELLS_ + 1023) / 1024, C_ / 4, 3 * B_);
    gather_split_kernel<<<g2, 256, 0, stream>>>(pf0, pf1, pf2, map, out);
}